// Round 20
// baseline (215.655 us; speedup 1.0000x reference)
//
#include <hip/hip_runtime.h>
#include <hip/hip_bf16.h>

#define NN 50000      // nodes
#define NE 800000     // edges
#define NR 20         // relations
#define NB 8          // bases
#define D  128        // hidden dim
#define DO 64         // output dim
#define NT 782        // ceil(NN/64) dst tiles
#define NBKT (NT*1280) // (tile, rel, dl) buckets = 1,000,960
#define NSB 978       // ceil(NBKT/1024)

typedef __attribute__((ext_vector_type(8))) short short8;
typedef __attribute__((ext_vector_type(4))) float f32x4;

__device__ inline unsigned short f2bf(float f) {
    __hip_bfloat16 h = __float2bfloat16(f);
    return *reinterpret_cast<unsigned short*>(&h);
}
__device__ inline float bf2f(unsigned short u) {
    unsigned x = ((unsigned)u) << 16;
    float f;
    __builtin_memcpy(&f, &x, 4);
    return f;
}

// ---------------------------------------------------------------------------
// ws layout (bytes):
//   [0        ..  4,003,840) cnt2    NBKT int  -- zeroed each call
//   [4,003,840..  4,007,752) bsum    NSB int   -- zeroed; scan1 writes totals,
//                                       last block converts to EXCLUSIVE prefix
//   [4,007,752..  4,007,756) scancnt int       -- zeroed each call
//   [4,007,808..  8,011,652) boff2   NBKT+1 int (BLOCK-LOCAL offsets)
//   [8,011,712.. 12,015,552) gcur2   NBKT int   (BLOCK-LOCAL cursors)
//   [12,015,616..12,025,856) W0      NR*D f32
//   [12,025,856..12,681,216) W1b     NR*16384 bf16 (B-fragment order)
//   [12,681,216..25,481,216) h1b     NN*D bf16
//   [25,481,216..27,081,216) epack   NE ushort (src ids, sorted by (tile,r,dl))
//   [28,681,216..28,697,600) linWb   lin_w in B-fragment order, bf16
// ---------------------------------------------------------------------------

// Fused hist+weights, role-split (no mixed-role straggler blocks):
//   blocks 0..781  : (tile,rel,dl) histogram only
//   blocks 782..821: weights build only
__global__ __launch_bounds__(1024) void k_wh(
        const int* __restrict__ dst, const int* __restrict__ et,
        const float* __restrict__ basis0, const float* __restrict__ wcomp0,
        const float* __restrict__ basis1, const float* __restrict__ wcomp1,
        const float* __restrict__ lin_w,
        int* __restrict__ cnt2, float* __restrict__ W0,
        unsigned short* __restrict__ W1b, unsigned short* __restrict__ linWb) {
    int b = blockIdx.x;
    if (b < NT) {
        int i = b * 1024 + threadIdx.x;
        if (i < NE) {
            int d = dst[i];
            int key = (d >> 6) * 1280 + et[i] * 64 + (d & 63);
            atomicAdd(&cnt2[key], 1);
        }
        return;
    }
    int idx = (b - NT) * 1024 + threadIdx.x;    // 0..40959
    if (idx < NR * D) {
        int r = idx / D, o = idx % D;
        float a = 0.f;
        #pragma unroll
        for (int bb = 0; bb < NB; bb++) a += wcomp0[r * NB + bb] * basis0[bb * D + o];
        W0[idx] = a;
    }
    if (idx < 16 * 64) {
        int lane = idx & 63, fr = idx >> 6;
        int kc = fr >> 2, nt = fr & 3;
        int i0 = kc * 32 + (lane >> 4) * 8;
        int o = nt * 16 + (lane & 15);
        short8 v;
        #pragma unroll
        for (int e = 0; e < 8; e++) v[e] = (short)f2bf(lin_w[(i0 + e) * DO + o]);
        *((short8*)linWb + idx) = v;
    }
    if (idx < NR * 4 * 8 * 64) {
        int lane = idx & 63;
        int cb   = (idx >> 6) & 7;
        int kc   = (idx >> 9) & 3;
        int rel  = idx >> 11;
        float wc[NB];
        #pragma unroll
        for (int bb = 0; bb < NB; bb++) wc[bb] = wcomp1[rel * NB + bb];
        int o  = cb * 16 + (lane & 15);
        int i0 = kc * 32 + (lane >> 4) * 8;
        short8 v;
        #pragma unroll
        for (int e = 0; e < 8; e++) {
            int i = i0 + e;
            float a = 0.f;
            #pragma unroll
            for (int bb = 0; bb < NB; bb++) a += wc[bb] * basis1[(bb * D + i) * D + o];
            v[e] = (short)f2bf(a);
        }
        *((short8*)W1b + idx) = v;
    }
}

// Single-pass scan: writes BLOCK-LOCAL offsets to boff2 AND gcur2; bsum gets
// block totals; the last-finishing block (scancnt ticket, r14-proven) converts
// bsum to an exclusive prefix in place. Consumers add bsum[i>>10] themselves.
__global__ __launch_bounds__(1024) void k_scan1(const int* __restrict__ cnt2,
                                                int* __restrict__ boff2,
                                                int* __restrict__ gcur2,
                                                int* __restrict__ bsum,
                                                int* __restrict__ scancnt) {
    __shared__ int ws[16];
    __shared__ int lastf;
    int t = threadIdx.x, lane = t & 63, wv = t >> 6;
    int i = blockIdx.x * 1024 + t;
    int v = (i < NBKT) ? cnt2[i] : 0;
    int inc = v;
    for (int dd = 1; dd < 64; dd <<= 1) {
        int u = __shfl_up(inc, dd);
        if (lane >= dd) inc += u;
    }
    if (lane == 63) ws[wv] = inc;
    __syncthreads();
    if (t == 0) { int a = 0; for (int j = 0; j < 16; j++) { int x = ws[j]; ws[j] = a; a += x; } }
    __syncthreads();
    int ex = ws[wv] + inc - v;
    if (i < NBKT) { boff2[i] = ex; gcur2[i] = ex; }
    if (i == NBKT) boff2[NBKT] = ex;             // local sentinel (block 977)
    if (t == 1023) {
        bsum[blockIdx.x] = ex + v;               // raw block total
        __threadfence();
        int done = atomicAdd(scancnt, 1);
        lastf = (done == (int)gridDim.x - 1);
    }
    __syncthreads();
    if (!lastf) return;
    // last block: exclusive-scan bsum in place (device-scope RMW reads)
    int v2 = (t < NSB) ? atomicAdd(&bsum[t], 0) : 0;
    int inc2 = v2;
    for (int dd = 1; dd < 64; dd <<= 1) {
        int u = __shfl_up(inc2, dd);
        if (lane >= dd) inc2 += u;
    }
    __syncthreads();
    if (lane == 63) ws[wv] = inc2;
    __syncthreads();
    if (t == 0) { int a = 0; for (int j = 0; j < 16; j++) { int x = ws[j]; ws[j] = a; a += x; } }
    __syncthreads();
    if (t < NSB) bsum[t] = ws[wv] + inc2 - v2;
}

// Fused scatter+h1, role-split:
//   blocks 0..781   : scatter (local cursor + bsum-prefix -> global position)
//   blocks 782..1563: h1 compute (tile = b - 782)
__global__ __launch_bounds__(1024) void k_sh(
        const int* __restrict__ src, const int* __restrict__ dst,
        const int* __restrict__ et, int* __restrict__ gcur2,
        const int* __restrict__ bpre,
        unsigned short* __restrict__ epack,
        const int* __restrict__ cnt2, const float* __restrict__ W0,
        const float* __restrict__ bias0, unsigned short* __restrict__ h1b) {
    int b = blockIdx.x, t = threadIdx.x;
    if (b < NT) {
        int i = b * 1024 + t;
        if (i < NE) {
            int d = dst[i];
            int key = (d >> 6) * 1280 + et[i] * 64 + (d & 63);
            int pos = atomicAdd(&gcur2[key], 1);      // block-local
            epack[pos + bpre[key >> 10]] = (unsigned short)src[i];
        }
        return;
    }
    __shared__ float cs[NR * 64];
    __shared__ float w0s[NR * D];
    int tile = b - NT;
    for (int j = t; j < NR * 64; j += 1024) cs[j] = (float)cnt2[tile * 1280 + j];
    for (int j = t; j < NR * D; j += 1024) w0s[j] = W0[j];
    __syncthreads();
    int nl = t >> 4, cg = t & 15;              // node-local, col-group of 8
    int n = tile * 64 + nl;
    if (n < NN) {
        float a[8];
        #pragma unroll
        for (int j = 0; j < 8; j++) a[j] = bias0[cg * 8 + j];
        for (int r = 0; r < NR; r++) {
            float c = cs[r * 64 + nl];
            #pragma unroll
            for (int j = 0; j < 8; j++) a[j] += c * w0s[r * D + cg * 8 + j];
        }
        short8 o;
        #pragma unroll
        for (int j = 0; j < 8; j++) o[j] = (short)f2bf(fmaxf(a[j], 0.f));
        *((short8*)(h1b + n * D + cg * 8)) = o;
    }
}

// Mega v12 (r15/r17/r19-proven, ~94 us profiled). Only prologue change:
// global offsets reconstructed as boff2(local) + bpre[gi>>10].
__global__ __launch_bounds__(512, 2) void k_mega(
        const unsigned short* __restrict__ epack, const int* __restrict__ boff2,
        const int* __restrict__ bpre,
        const unsigned short* __restrict__ h1b,
        const unsigned short* __restrict__ W1b,
        const unsigned short* __restrict__ linWb,
        const float* __restrict__ bias1, const float* __restrict__ lin_b,
        float* __restrict__ out) {
    __shared__ __align__(16) char lds[17408 + 16384];  // Raw 64x17s8 | Sl 64x16s8
    __shared__ unsigned short ooffs[1282];             // tile-relative offsets
    __shared__ unsigned short epk[2048];               // tile's src ids

    short8* Raw8 = (short8*)lds;
    short8* Sl8  = (short8*)(lds + 17408);

    int t = threadIdx.x, tile = blockIdx.x;
    int wv = t >> 6, lane = t & 63;
    int le = t >> 3, lp = t & 7;             // stage role: edge row, 16B pair
    int dl = t >> 3, cg = t & 7;             // reduce role: dst-local, col-group
    int row = lane & 15, gg = lane >> 4;     // mfma role

    int kbase = tile * 1280;
    int tbg = boff2[kbase] + bpre[kbase >> 10];
    for (int i = t; i < 1281; i += 512) {
        int gi = kbase + i;
        ooffs[i] = (unsigned short)(boff2[gi] + bpre[gi >> 10] - tbg);
    }
    __syncthreads();
    int nE = min((int)ooffs[1280], 2048);
    for (int i = t; i < nE; i += 512) epk[i] = epack[tbg + i];
    __syncthreads();

    f32x4 acc[4];
    #pragma unroll
    for (int j = 0; j < 4; j++) acc[j] = (f32x4){0.f, 0.f, 0.f, 0.f};

    for (int r = 0; r < NR; r++) {
        int rbase = ooffs[r * 64];
        int cnt = ooffs[r * 64 + 64] - rbase;    // block-uniform
        if (cnt == 0) continue;

        const short8* Wg8 = (const short8*)W1b + r * 2048;
        short8 breg[4];
        #pragma unroll
        for (int kc = 0; kc < 4; kc++) breg[kc] = Wg8[(kc * 8 + wv) * 64 + lane];

        float s[16];
        #pragma unroll
        for (int k = 0; k < 16; k++) s[k] = 0.f;
        int o0 = ooffs[r * 64 + dl] - rbase;
        int o1 = ooffs[r * 64 + dl + 1] - rbase;
        int nc = (cnt + 63) >> 6;

        for (int c = 0; c < nc; c++) {
            int cb0 = c * 64, m = min(64, cnt - cb0);
            if (c > 0) __syncthreads();          // prev reduce done, Raw reusable
            if (le < m) {
                int node = epk[rbase + cb0 + le];
                const short8* hp = (const short8*)(h1b + (size_t)node * D) + lp * 2;
                Raw8[le * 17 + lp * 2]     = hp[0];
                Raw8[le * 17 + lp * 2 + 1] = hp[1];
            }
            __syncthreads();                     // Raw visible
            int lo = max(o0 - cb0, 0), hi = min(o1 - cb0, m);
            for (int p = lo; p < hi; p++) {
                short8 w0 = Raw8[p * 17 + 2 * cg];
                short8 w1 = Raw8[p * 17 + 2 * cg + 1];
                #pragma unroll
                for (int k = 0; k < 8; k++) {
                    s[k]     += bf2f((unsigned short)w0[k]);
                    s[8 + k] += bf2f((unsigned short)w1[k]);
                }
            }
        }
        short8 p0, p1;
        #pragma unroll
        for (int k = 0; k < 8; k++) {
            p0[k] = (short)f2bf(s[k]);
            p1[k] = (short)f2bf(s[8 + k]);
        }
        Sl8[dl * 16 + ((cg * 2)     ^ (dl & 15))] = p0;
        Sl8[dl * 16 + ((cg * 2 + 1) ^ (dl & 15))] = p1;
        __syncthreads();                         // Sl visible (all reduces done)
        #pragma unroll
        for (int rb = 0; rb < 4; rb++) {
            int arow = rb * 16 + row;
            #pragma unroll
            for (int kc = 0; kc < 4; kc++) {
                short8 a = Sl8[arow * 16 + ((kc * 4 + gg) ^ (arow & 15))];
                acc[rb] = __builtin_amdgcn_mfma_f32_16x16x32_bf16(a, breg[kc], acc[rb], 0, 0, 0);
            }
        }
    }

    __syncthreads();                             // last-rel Sl reads done
    // epilogue part 1: bias + relu -> bf16 Af[64][136] (aliases Raw region)
    unsigned short* Af = (unsigned short*)lds;
    #pragma unroll
    for (int rb = 0; rb < 4; rb++) {
        #pragma unroll
        for (int reg = 0; reg < 4; reg++) {
            int rr = rb * 16 + gg * 4 + reg;
            int col = wv * 16 + row;
            Af[rr * 136 + col] = f2bf(fmaxf(acc[rb][reg] + bias1[col], 0.f));
        }
    }
    __syncthreads();
    // epilogue part 2: out[64x64] = Af @ lin_w + lin_b via MFMA
    {
        int rb = wv & 3;
        int nt0 = (wv >> 2) * 2, nt1 = nt0 + 1;
        f32x4 ao0 = (f32x4){0.f, 0.f, 0.f, 0.f};
        f32x4 ao1 = (f32x4){0.f, 0.f, 0.f, 0.f};
        #pragma unroll
        for (int kc = 0; kc < 4; kc++) {
            short8 a = *(const short8*)(Af + (rb * 16 + row) * 136 + kc * 32 + gg * 8);
            short8 b0 = *((const short8*)linWb + (kc * 4 + nt0) * 64 + lane);
            short8 b1 = *((const short8*)linWb + (kc * 4 + nt1) * 64 + lane);
            ao0 = __builtin_amdgcn_mfma_f32_16x16x32_bf16(a, b0, ao0, 0, 0, 0);
            ao1 = __builtin_amdgcn_mfma_f32_16x16x32_bf16(a, b1, ao1, 0, 0, 0);
        }
        float lb0 = lin_b[nt0 * 16 + row];
        float lb1 = lin_b[nt1 * 16 + row];
        #pragma unroll
        for (int reg = 0; reg < 4; reg++) {
            int d = tile * 64 + rb * 16 + gg * 4 + reg;
            if (d < NN) {
                out[d * DO + nt0 * 16 + row] = ao0[reg] + lb0;
                out[d * DO + nt1 * 16 + row] = ao1[reg] + lb1;
            }
        }
    }
}

extern "C" void kernel_launch(void* const* d_in, const int* in_sizes, int n_in,
                              void* d_out, int out_size, void* d_ws, size_t ws_size,
                              hipStream_t stream) {
    const int*   src    = (const int*)d_in[0];
    const int*   dst    = (const int*)d_in[1];
    const int*   et     = (const int*)d_in[2];
    const float* basis0 = (const float*)d_in[4];
    const float* wcomp0 = (const float*)d_in[5];
    const float* bias0  = (const float*)d_in[6];
    const float* basis1 = (const float*)d_in[7];
    const float* wcomp1 = (const float*)d_in[8];
    const float* bias1  = (const float*)d_in[9];
    const float* lin_w  = (const float*)d_in[10];
    const float* lin_b  = (const float*)d_in[11];
    float* out = (float*)d_out;

    char* ws = (char*)d_ws;
    int*            cnt2    = (int*)           (ws + 0);
    int*            bsum    = (int*)           (ws + 4003840);
    int*            scancnt = (int*)           (ws + 4007752);
    int*            boff2   = (int*)           (ws + 4007808);
    int*            gcur2   = (int*)           (ws + 8011712);
    float*          W0      = (float*)         (ws + 12015616);
    unsigned short* W1b     = (unsigned short*)(ws + 12025856);
    unsigned short* h1b     = (unsigned short*)(ws + 12681216);
    unsigned short* epack   = (unsigned short*)(ws + 25481216);
    unsigned short* linWb   = (unsigned short*)(ws + 28681216);

    // zero cnt2 + bsum + scancnt
    hipMemsetAsync(ws, 0, 4007756, stream);

    k_wh<<<NT + 40, 1024, 0, stream>>>(dst, et, basis0, wcomp0, basis1, wcomp1,
                                       lin_w, cnt2, W0, W1b, linWb);
    k_scan1<<<NSB, 1024, 0, stream>>>(cnt2, boff2, gcur2, bsum, scancnt);
    k_sh<<<NT * 2, 1024, 0, stream>>>(src, dst, et, gcur2, bsum, epack,
                                      cnt2, W0, bias0, h1b);
    k_mega<<<NT, 512, 0, stream>>>(epack, boff2, bsum, h1b, W1b, linWb,
                                   bias1, lin_b, out);
}

// Round 21
// 187.015 us; speedup vs baseline: 1.1531x; 1.1531x over previous
//
#include <hip/hip_runtime.h>
#include <hip/hip_bf16.h>

#define NN 50000      // nodes
#define NE 800000     // edges
#define NR 20         // relations
#define NB 8          // bases
#define D  128        // hidden dim
#define DO 64         // output dim
#define NT 782        // ceil(NN/64) dst tiles
#define NBKT (NT*1280) // (tile, rel, dl) buckets = 1,000,960
#define NSB 978       // ceil(NBKT/1024)

typedef __attribute__((ext_vector_type(8))) short short8;
typedef __attribute__((ext_vector_type(4))) float f32x4;

__device__ inline unsigned short f2bf(float f) {
    __hip_bfloat16 h = __float2bfloat16(f);
    return *reinterpret_cast<unsigned short*>(&h);
}
__device__ inline float bf2f(unsigned short u) {
    unsigned x = ((unsigned)u) << 16;
    float f;
    __builtin_memcpy(&f, &x, 4);
    return f;
}

// ---------------------------------------------------------------------------
// ws layout (bytes):
//   [0        ..  4,003,840) cnt2    NBKT int  -- zeroed each call
//   [4,003,840..  4,007,752) bsum    NSB int   -- rewritten by scan1 (raw totals)
//   [4,007,808..  8,011,652) boff2   NBKT+1 int
//   [8,011,712.. 12,015,552) gcur2   NBKT int
//   [12,015,616..12,025,856) W0      NR*D f32
//   [12,025,856..12,681,216) W1b     NR*16384 bf16 (B-fragment order)
//   [12,681,216..25,481,216) h1b     NN*D bf16
//   [25,481,216..27,081,216) epack   NE ushort (src ids, sorted by (tile,r,dl))
//   [28,681,216..28,697,600) linWb   lin_w in B-fragment order, bf16
// ---------------------------------------------------------------------------

// Fused hist+weights, role-split (no mixed-role straggler blocks):
//   blocks 0..781  : (tile,rel,dl) histogram only
//   blocks 782..821: weights build only (idx = (b-782)*1024 + t covers 40960)
__global__ __launch_bounds__(1024) void k_wh(
        const int* __restrict__ dst, const int* __restrict__ et,
        const float* __restrict__ basis0, const float* __restrict__ wcomp0,
        const float* __restrict__ basis1, const float* __restrict__ wcomp1,
        const float* __restrict__ lin_w,
        int* __restrict__ cnt2, float* __restrict__ W0,
        unsigned short* __restrict__ W1b, unsigned short* __restrict__ linWb) {
    int b = blockIdx.x;
    if (b < NT) {
        int i = b * 1024 + threadIdx.x;
        if (i < NE) {
            int d = dst[i];
            int key = (d >> 6) * 1280 + et[i] * 64 + (d & 63);
            atomicAdd(&cnt2[key], 1);
        }
        return;
    }
    int idx = (b - NT) * 1024 + threadIdx.x;    // 0..40959
    if (idx < NR * D) {
        int r = idx / D, o = idx % D;
        float a = 0.f;
        #pragma unroll
        for (int bb = 0; bb < NB; bb++) a += wcomp0[r * NB + bb] * basis0[bb * D + o];
        W0[idx] = a;
    }
    if (idx < 16 * 64) {
        int lane = idx & 63, fr = idx >> 6;
        int kc = fr >> 2, nt = fr & 3;
        int i0 = kc * 32 + (lane >> 4) * 8;
        int o = nt * 16 + (lane & 15);
        short8 v;
        #pragma unroll
        for (int e = 0; e < 8; e++) v[e] = (short)f2bf(lin_w[(i0 + e) * DO + o]);
        *((short8*)linWb + idx) = v;
    }
    if (idx < NR * 4 * 8 * 64) {
        int lane = idx & 63;
        int cb   = (idx >> 6) & 7;
        int kc   = (idx >> 9) & 3;
        int rel  = idx >> 11;
        float wc[NB];
        #pragma unroll
        for (int bb = 0; bb < NB; bb++) wc[bb] = wcomp1[rel * NB + bb];
        int o  = cb * 16 + (lane & 15);
        int i0 = kc * 32 + (lane >> 4) * 8;
        short8 v;
        #pragma unroll
        for (int e = 0; e < 8; e++) {
            int i = i0 + e;
            float a = 0.f;
            #pragma unroll
            for (int bb = 0; bb < NB; bb++) a += wc[bb] * basis1[(bb * D + i) * D + o];
            v[e] = (short)f2bf(a);
        }
        *((short8*)W1b + idx) = v;
    }
}

__global__ __launch_bounds__(1024) void k_scan1(const int* __restrict__ cnt2,
                                                int* __restrict__ boff2,
                                                int* __restrict__ bsum) {
    __shared__ int ws[16];
    int t = threadIdx.x, lane = t & 63, wv = t >> 6;
    int i = blockIdx.x * 1024 + t;
    int v = (i < NBKT) ? cnt2[i] : 0;
    int inc = v;
    for (int dd = 1; dd < 64; dd <<= 1) {
        int u = __shfl_up(inc, dd);
        if (lane >= dd) inc += u;
    }
    if (lane == 63) ws[wv] = inc;
    __syncthreads();
    if (t == 0) { int a = 0; for (int j = 0; j < 16; j++) { int x = ws[j]; ws[j] = a; a += x; } }
    __syncthreads();
    int ex = ws[wv] + inc - v;
    if (i < NBKT) boff2[i] = ex;
    if (t == 1023) bsum[blockIdx.x] = ex + v;   // raw block total (not scanned)
}

// scan3 with scan2 folded in: block b computes sum(bsum[0..b-1]) itself
// (one 1024-thread reduction over the L2-hot 978-entry bsum array).
__global__ __launch_bounds__(1024) void k_scan3(int* __restrict__ boff2,
                                                const int* __restrict__ bsum,
                                                int* __restrict__ gcur2) {
    __shared__ int ws[16];
    __shared__ int basesh;
    int t = threadIdx.x, lane = t & 63, wv = t >> 6;
    int b = blockIdx.x;
    int v = (t < b) ? bsum[t] : 0;               // b <= 977 < 1024: one pass
    #pragma unroll
    for (int dd = 1; dd < 64; dd <<= 1) v += __shfl_xor(v, dd);
    if (lane == 0) ws[wv] = v;
    __syncthreads();
    if (t == 0) { int a = 0; for (int j = 0; j < 16; j++) a += ws[j]; basesh = a; }
    __syncthreads();
    int base = basesh;
    int i = b * 1024 + t;
    if (i < NBKT) {
        int f = boff2[i] + base;
        boff2[i] = f;
        gcur2[i] = f;
    }
    if (i == 0) boff2[NBKT] = NE;
}

// Fused scatter+h1, role-split:
//   blocks 0..781   : counting-sort scatter only
//   blocks 782..1563: h1 compute only (tile = b - 782)
__global__ __launch_bounds__(1024) void k_sh(
        const int* __restrict__ src, const int* __restrict__ dst,
        const int* __restrict__ et, int* __restrict__ gcur2,
        unsigned short* __restrict__ epack,
        const int* __restrict__ cnt2, const float* __restrict__ W0,
        const float* __restrict__ bias0, unsigned short* __restrict__ h1b) {
    int b = blockIdx.x, t = threadIdx.x;
    if (b < NT) {
        int i = b * 1024 + t;
        if (i < NE) {
            int d = dst[i];
            int key = (d >> 6) * 1280 + et[i] * 64 + (d & 63);
            int pos = atomicAdd(&gcur2[key], 1);
            epack[pos] = (unsigned short)src[i];
        }
        return;
    }
    __shared__ float cs[NR * 64];
    __shared__ float w0s[NR * D];
    int tile = b - NT;
    for (int j = t; j < NR * 64; j += 1024) cs[j] = (float)cnt2[tile * 1280 + j];
    for (int j = t; j < NR * D; j += 1024) w0s[j] = W0[j];
    __syncthreads();
    int nl = t >> 4, cg = t & 15;              // node-local, col-group of 8
    int n = tile * 64 + nl;
    if (n < NN) {
        float a[8];
        #pragma unroll
        for (int j = 0; j < 8; j++) a[j] = bias0[cg * 8 + j];
        for (int r = 0; r < NR; r++) {
            float c = cs[r * 64 + nl];
            #pragma unroll
            for (int j = 0; j < 8; j++) a[j] += c * w0s[r * D + cg * 8 + j];
        }
        short8 o;
        #pragma unroll
        for (int j = 0; j < 8; j++) o[j] = (short)f2bf(fmaxf(a[j], 0.f));
        *((short8*)(h1b + n * D + cg * 8)) = o;
    }
}

// Mega v12 (r15/r17/r19-proven, ~94 us profiled): r13 body + epk/ooffs in LDS.
// 512 thr / 64-dst tile; wave wv owns output cols wv*16..+15 for all 64 rows.
// Per rel: 4 B-frag register loads (reused 4x) at rel-top; stage 64 rows ->
// Raw (node ids from LDS epk); reduce own bucket; publish swizzled Sl;
// 16 MFMA. 2 barriers/rel. No pipelining, no setprio (r16 showed both hurt).
__global__ __launch_bounds__(512, 2) void k_mega(
        const unsigned short* __restrict__ epack, const int* __restrict__ boff2,
        const unsigned short* __restrict__ h1b,
        const unsigned short* __restrict__ W1b,
        const unsigned short* __restrict__ linWb,
        const float* __restrict__ bias1, const float* __restrict__ lin_b,
        float* __restrict__ out) {
    __shared__ __align__(16) char lds[17408 + 16384];  // Raw 64x17s8 | Sl 64x16s8
    __shared__ unsigned short ooffs[1282];             // tile-relative offsets
    __shared__ unsigned short epk[2048];               // tile's src ids

    short8* Raw8 = (short8*)lds;
    short8* Sl8  = (short8*)(lds + 17408);

    int t = threadIdx.x, tile = blockIdx.x;
    int wv = t >> 6, lane = t & 63;
    int le = t >> 3, lp = t & 7;             // stage role: edge row, 16B pair
    int dl = t >> 3, cg = t & 7;             // reduce role: dst-local, col-group
    int row = lane & 15, gg = lane >> 4;     // mfma role

    int kbase = tile * 1280;
    int tb = boff2[kbase];
    for (int i = t; i < 1281; i += 512)
        ooffs[i] = (unsigned short)(boff2[kbase + i] - tb);
    __syncthreads();
    int nE = min((int)ooffs[1280], 2048);
    for (int i = t; i < nE; i += 512) epk[i] = epack[tb + i];
    __syncthreads();

    f32x4 acc[4];
    #pragma unroll
    for (int j = 0; j < 4; j++) acc[j] = (f32x4){0.f, 0.f, 0.f, 0.f};

    for (int r = 0; r < NR; r++) {
        int rbase = ooffs[r * 64];
        int cnt = ooffs[r * 64 + 64] - rbase;    // block-uniform
        if (cnt == 0) continue;

        const short8* Wg8 = (const short8*)W1b + r * 2048;
        short8 breg[4];
        #pragma unroll
        for (int kc = 0; kc < 4; kc++) breg[kc] = Wg8[(kc * 8 + wv) * 64 + lane];

        float s[16];
        #pragma unroll
        for (int k = 0; k < 16; k++) s[k] = 0.f;
        int o0 = ooffs[r * 64 + dl] - rbase;
        int o1 = ooffs[r * 64 + dl + 1] - rbase;
        int nc = (cnt + 63) >> 6;

        for (int c = 0; c < nc; c++) {
            int cb0 = c * 64, m = min(64, cnt - cb0);
            if (c > 0) __syncthreads();          // prev reduce done, Raw reusable
            if (le < m) {
                int node = epk[rbase + cb0 + le];
                const short8* hp = (const short8*)(h1b + (size_t)node * D) + lp * 2;
                Raw8[le * 17 + lp * 2]     = hp[0];
                Raw8[le * 17 + lp * 2 + 1] = hp[1];
            }
            __syncthreads();                     // Raw visible
            int lo = max(o0 - cb0, 0), hi = min(o1 - cb0, m);
            for (int p = lo; p < hi; p++) {
                short8 w0 = Raw8[p * 17 + 2 * cg];
                short8 w1 = Raw8[p * 17 + 2 * cg + 1];
                #pragma unroll
                for (int k = 0; k < 8; k++) {
                    s[k]     += bf2f((unsigned short)w0[k]);
                    s[8 + k] += bf2f((unsigned short)w1[k]);
                }
            }
        }
        short8 p0, p1;
        #pragma unroll
        for (int k = 0; k < 8; k++) {
            p0[k] = (short)f2bf(s[k]);
            p1[k] = (short)f2bf(s[8 + k]);
        }
        Sl8[dl * 16 + ((cg * 2)     ^ (dl & 15))] = p0;
        Sl8[dl * 16 + ((cg * 2 + 1) ^ (dl & 15))] = p1;
        __syncthreads();                         // Sl visible (all reduces done)
        #pragma unroll
        for (int rb = 0; rb < 4; rb++) {
            int arow = rb * 16 + row;
            #pragma unroll
            for (int kc = 0; kc < 4; kc++) {
                short8 a = Sl8[arow * 16 + ((kc * 4 + gg) ^ (arow & 15))];
                acc[rb] = __builtin_amdgcn_mfma_f32_16x16x32_bf16(a, breg[kc], acc[rb], 0, 0, 0);
            }
        }
    }

    __syncthreads();                             // last-rel Sl reads done
    // epilogue part 1: bias + relu -> bf16 Af[64][136] (aliases Raw region)
    unsigned short* Af = (unsigned short*)lds;
    #pragma unroll
    for (int rb = 0; rb < 4; rb++) {
        #pragma unroll
        for (int reg = 0; reg < 4; reg++) {
            int rr = rb * 16 + gg * 4 + reg;
            int col = wv * 16 + row;
            Af[rr * 136 + col] = f2bf(fmaxf(acc[rb][reg] + bias1[col], 0.f));
        }
    }
    __syncthreads();
    // epilogue part 2: out[64x64] = Af @ lin_w + lin_b via MFMA
    {
        int rb = wv & 3;
        int nt0 = (wv >> 2) * 2, nt1 = nt0 + 1;
        f32x4 ao0 = (f32x4){0.f, 0.f, 0.f, 0.f};
        f32x4 ao1 = (f32x4){0.f, 0.f, 0.f, 0.f};
        #pragma unroll
        for (int kc = 0; kc < 4; kc++) {
            short8 a = *(const short8*)(Af + (rb * 16 + row) * 136 + kc * 32 + gg * 8);
            short8 b0 = *((const short8*)linWb + (kc * 4 + nt0) * 64 + lane);
            short8 b1 = *((const short8*)linWb + (kc * 4 + nt1) * 64 + lane);
            ao0 = __builtin_amdgcn_mfma_f32_16x16x32_bf16(a, b0, ao0, 0, 0, 0);
            ao1 = __builtin_amdgcn_mfma_f32_16x16x32_bf16(a, b1, ao1, 0, 0, 0);
        }
        float lb0 = lin_b[nt0 * 16 + row];
        float lb1 = lin_b[nt1 * 16 + row];
        #pragma unroll
        for (int reg = 0; reg < 4; reg++) {
            int d = tile * 64 + rb * 16 + gg * 4 + reg;
            if (d < NN) {
                out[d * DO + nt0 * 16 + row] = ao0[reg] + lb0;
                out[d * DO + nt1 * 16 + row] = ao1[reg] + lb1;
            }
        }
    }
}

extern "C" void kernel_launch(void* const* d_in, const int* in_sizes, int n_in,
                              void* d_out, int out_size, void* d_ws, size_t ws_size,
                              hipStream_t stream) {
    const int*   src    = (const int*)d_in[0];
    const int*   dst    = (const int*)d_in[1];
    const int*   et     = (const int*)d_in[2];
    const float* basis0 = (const float*)d_in[4];
    const float* wcomp0 = (const float*)d_in[5];
    const float* bias0  = (const float*)d_in[6];
    const float* basis1 = (const float*)d_in[7];
    const float* wcomp1 = (const float*)d_in[8];
    const float* bias1  = (const float*)d_in[9];
    const float* lin_w  = (const float*)d_in[10];
    const float* lin_b  = (const float*)d_in[11];
    float* out = (float*)d_out;

    char* ws = (char*)d_ws;
    int*            cnt2    = (int*)           (ws + 0);
    int*            bsum    = (int*)           (ws + 4003840);
    int*            boff2   = (int*)           (ws + 4007808);
    int*            gcur2   = (int*)           (ws + 8011712);
    float*          W0      = (float*)         (ws + 12015616);
    unsigned short* W1b     = (unsigned short*)(ws + 12025856);
    unsigned short* h1b     = (unsigned short*)(ws + 12681216);
    unsigned short* epack   = (unsigned short*)(ws + 25481216);
    unsigned short* linWb   = (unsigned short*)(ws + 28681216);

    hipMemsetAsync(ws, 0, 4003840, stream);   // zero cnt2

    k_wh<<<NT + 40, 1024, 0, stream>>>(dst, et, basis0, wcomp0, basis1, wcomp1,
                                       lin_w, cnt2, W0, W1b, linWb);
    k_scan1<<<NSB, 1024, 0, stream>>>(cnt2, boff2, bsum);
    k_scan3<<<NSB, 1024, 0, stream>>>(boff2, bsum, gcur2);
    k_sh<<<NT * 2, 1024, 0, stream>>>(src, dst, et, gcur2, epack,
                                      cnt2, W0, bias0, h1b);
    k_mega<<<NT, 512, 0, stream>>>(epack, boff2, h1b, W1b, linWb,
                                   bias1, lin_b, out);
}